// Round 6
// baseline (218.033 us; speedup 1.0000x reference)
//
#include <hip/hip_runtime.h>

typedef __bf16 bf16x8 __attribute__((ext_vector_type(8)));
typedef unsigned short us8 __attribute__((ext_vector_type(8)));
typedef unsigned short us2 __attribute__((ext_vector_type(2)));
typedef float f32x16 __attribute__((ext_vector_type(16)));

#define N_IMG 32
#define CI 16
#define HH 256
#define WW 256
#define CO 64
#define OHH 254
#define OWW 254

#define SC 16       // shorts per (row,w) cell: 32B (R1 proved ~= SC24 perf)
#define SLOTS 6     // 6-row ring: read oh..oh+3, write oh+4,oh+5
#define XS_W 258    // 256 + 2 zero-pad columns
#define NSTRIP 24   // 32*24 = 768 blocks = exactly 3 resident/CU
#define WP_SHORTS (CO * 160)
#define WS_NEEDED ((size_t)WP_SHORTS * 2)

__device__ __forceinline__ unsigned short f2bf(float f) {
  union { float f; unsigned u; } v; v.f = f;
  return (unsigned short)((v.u + 0x7FFFu + ((v.u >> 16) & 1u)) >> 16);  // RNE
}

#if defined(__has_builtin)
#if __has_builtin(__builtin_amdgcn_cvt_pk_bf16_f32)
#define HAVE_CVT_PK 1
#endif
#endif

__device__ __forceinline__ us2 cvt2(float a, float b) {
#ifdef HAVE_CVT_PK
  typedef __bf16 bf16x2 __attribute__((ext_vector_type(2)));
  bf16x2 r = __builtin_amdgcn_cvt_pk_bf16_f32(a, b);  // lo=a, hi=b, RNE
  return __builtin_bit_cast(us2, r);
#else
  us2 r; r[0] = f2bf(a); r[1] = f2bf(b); return r;
#endif
}

__device__ __forceinline__ float fast_tanh(float x) {
  float cx = fminf(fmaxf(x, -15.f), 15.f);
  float e = __expf(2.f * cx);
  return (e - 1.f) / (e + 1.f);
}

// ---- prep: weights+bias -> bf16 A-side layout wp[oc][tap*16+ci] (20 KB) ----
__global__ void prep_w(const float* __restrict__ wg, const float* __restrict__ bg,
                       unsigned short* __restrict__ wp) {
  int idx = blockIdx.x * 256 + threadIdx.x;
  if (idx >= WP_SHORTS) return;
  int oc = idx / 160;
  int k = idx - oc * 160;
  int tap = k >> 4, ci = k & 15;
  float v;
  if (tap < 9)      v = wg[oc * 144 + ci * 9 + tap];
  else if (ci == 0) v = bg[oc];
  else              v = 0.f;
  wp[idx] = f2bf(v);
}

// ---- fused conv+min+tanh: 2-ROW-PER-ITERATION rolling-window kernel ----
// Diagnosis (R4 counters, held across R0-R5 variants): every pipe <21%,
// 1.2 TB/s effective -- iteration wall ~= ONE loaded-memory round-trip per
// output row (16 dword loads/wave in flight is too little concurrency).
// Fix: amortize the latency over 2 rows -- per iteration load rows oh+4 and
// oh+5 (32 dwords outstanding, 2x bytes in flight), compute rows oh,oh+1
// (80 MFMAs of latency cover), stage both, ONE __syncthreads. Iterations
// halve. Ring = 6 slots (slot = (row-oh0) mod 6), SC=16 keeps LDS 48.4 KB
// -> 3 blocks/CU. Plain __syncthreads (R3-proven codegen; R2/R5 showed
// asm-barrier variants are neutral or wreck regalloc).
// Ring safety: iter reads slots sb..sb+3, writes sb+4,sb+5 (mod 6) --
// disjoint residues, and the write targets were last read one barrier ago.
// Numerics identical to the 213us baseline (same cvt, MFMA order; fmin
// tree is a bit-exact reassociation).
__global__ __launch_bounds__(256, 3)
void conv_fused(const float* __restrict__ xg, const unsigned short* __restrict__ wp,
                float* __restrict__ out) {
  __shared__ __align__(16) unsigned short xs[SLOTS * XS_W * SC];  // 48.4 KB
  const int t = threadIdx.x;
  const int n = blockIdx.x / NSTRIP;
  const int s = blockIdx.x - n * NSTRIP;
  // 254 rows over 24 strips, all EVEN: 7 strips of 12, 17 strips of 10
  const int oh0 = (s < 7) ? 12 * s : 84 + 10 * (s - 7);
  const int nrows = (s < 7) ? 12 : 10;
  const int oh1 = oh0 + nrows;

  const float* srcT = xg + (size_t)n * (CI * HH * WW) + t;

  // zero pad columns w=256,257 for all 6 ring slots (persist; never rewritten)
  if (t < 32 * SLOTS) {
    const int slot = t >> 5, rem = t & 31;
    xs[(slot * XS_W + 256 + (rem >> 4)) * SC + (rem & 15)] = 0;
  }

  // ---- prologue: stage input rows oh0..oh0+3 into slots 0..3 (2 batches) ----
#pragma unroll
  for (int b = 0; b < 2; ++b) {
    float v[2][16];
#pragma unroll
    for (int r = 0; r < 2; ++r)
#pragma unroll
      for (int j = 0; j < 16; ++j)
        v[r][j] = srcT[((size_t)j * HH + (oh0 + 2 * b + r)) * WW];
#pragma unroll
    for (int r = 0; r < 2; ++r) {
      union { us8 v8[2]; us2 v2[8]; } pk;
#pragma unroll
      for (int j = 0; j < 8; ++j) pk.v2[j] = cvt2(v[r][2 * j], v[r][2 * j + 1]);
      unsigned short* cell = xs + ((2 * b + r) * XS_W + t) * SC;
      *(us8*)(cell) = pk.v8[0];      // ds_write_b128
      *(us8*)(cell + 8) = pk.v8[1];  // ds_write_b128
    }
  }

  const int lane = t & 63, wave = t >> 6;
  const int lr = lane & 31, qh = lane >> 5;

  // preload A-frags ONCE into registers (2 mt x 10 taps x 4 VGPR = 80 VGPRs)
  const unsigned short* wpl = wp + lr * 160 + qh * 8;
  bf16x8 afrag[2][10];
#pragma unroll
  for (int mt = 0; mt < 2; ++mt)
#pragma unroll
    for (int tap = 0; tap < 10; ++tap)
      afrag[mt][tap] =
          __builtin_bit_cast(bf16x8, *(const us8*)(wpl + mt * 32 * 160 + tap * 16));

  us8 onev = {};
  if (qh == 0) onev[0] = 0x3F80;
  const bf16x8 xone = __builtin_bit_cast(bf16x8, onev);

  const int pb = wave * 64;  // this wave's 64-pixel strip

  __syncthreads();

  int sb = 0;  // ring slot of input row oh
  for (int oh = oh0; oh < oh1; oh += 2) {
    const bool do_stage = (oh + 4 <= oh1 + 1);  // last iter stages nothing

    // issue BOTH next rows' loads first: 32 dwords/thread in flight,
    // covered by the 80-MFMA phase below
    float v4[16], v5[16];
    if (do_stage) {
#pragma unroll
      for (int j = 0; j < 16; ++j)
        v4[j] = srcT[((size_t)j * HH + (oh + 4)) * WW];
#pragma unroll
      for (int j = 0; j < 16; ++j)
        v5[j] = srcT[((size_t)j * HH + (oh + 5)) * WW];
    }

    // slot byte bases for input rows oh..oh+3 (block-uniform -> SGPRs)
    int so[4];
#pragma unroll
    for (int kh = 0; kh < 4; ++kh) {
      int sl = sb + kh;
      if (sl >= SLOTS) sl -= SLOTS;
      so[kh] = sl * (XS_W * SC);
    }

#pragma unroll
    for (int r2 = 0; r2 < 2; ++r2) {  // output rows oh, oh+1
      float vmin[2];
#pragma unroll
      for (int nt = 0; nt < 2; ++nt) {  // sequential nt: acc = 32 VGPR
        f32x16 acc0, acc1;
#pragma unroll
        for (int e = 0; e < 16; ++e) { acc0[e] = 0.f; acc1[e] = 0.f; }
#pragma unroll
        for (int tap = 0; tap < 9; ++tap) {
          const int kh = tap / 3, kw = tap - kh * 3;
          bf16x8 xf = __builtin_bit_cast(
              bf16x8, *(const us8*)(xs + so[r2 + kh] +
                                    (pb + nt * 32 + lr + kw) * SC + qh * 8));
          acc0 = __builtin_amdgcn_mfma_f32_32x32x16_bf16(afrag[0][tap], xf, acc0, 0, 0, 0);
          acc1 = __builtin_amdgcn_mfma_f32_32x32x16_bf16(afrag[1][tap], xf, acc1, 0, 0, 0);
        }
        // bias tap: B = e_{k=144}
        acc0 = __builtin_amdgcn_mfma_f32_32x32x16_bf16(afrag[0][9], xone, acc0, 0, 0, 0);
        acc1 = __builtin_amdgcn_mfma_f32_32x32x16_bf16(afrag[1][9], xone, acc1, 0, 0, 0);

        // tree min (bit-exact reassociation)
        f32x16 m;
#pragma unroll
        for (int e = 0; e < 16; ++e) m[e] = fminf(acc0[e], acc1[e]);
#pragma unroll
        for (int e = 0; e < 8; ++e) m[e] = fminf(m[e], m[e + 8]);
#pragma unroll
        for (int e = 0; e < 4; ++e) m[e] = fminf(m[e], m[e + 4]);
        float mv = fminf(fminf(m[0], m[1]), fminf(m[2], m[3]));
        mv = fminf(mv, __shfl_xor(mv, 32, 64));
        vmin[nt] = fast_tanh(fast_tanh(mv));
      }
      const float res = (lane < 32) ? vmin[0] : vmin[1];
      const int ow = pb + lane;
      if (ow < OWW) out[((size_t)n * OHH + (oh + r2)) * OWW + ow] = res;
    }

    // convert + write rows oh+4, oh+5 into slots sb+4, sb+5 (mod 6) --
    // disjoint from this iteration's read slots sb..sb+3
    if (do_stage) {
      int s4 = sb + 4; if (s4 >= SLOTS) s4 -= SLOTS;
      int s5 = sb + 5; if (s5 >= SLOTS) s5 -= SLOTS;
      {
        union { us8 v8[2]; us2 v2[8]; } pk;
#pragma unroll
        for (int j = 0; j < 8; ++j) pk.v2[j] = cvt2(v4[2 * j], v4[2 * j + 1]);
        unsigned short* cell = xs + (s4 * XS_W + t) * SC;
        *(us8*)(cell) = pk.v8[0];
        *(us8*)(cell + 8) = pk.v8[1];
      }
      {
        union { us8 v8[2]; us2 v2[8]; } pk;
#pragma unroll
        for (int j = 0; j < 8; ++j) pk.v2[j] = cvt2(v5[2 * j], v5[2 * j + 1]);
        unsigned short* cell = xs + (s5 * XS_W + t) * SC;
        *(us8*)(cell) = pk.v8[0];
        *(us8*)(cell + 8) = pk.v8[1];
      }
    }

    __syncthreads();
    sb += 2;
    if (sb >= SLOTS) sb -= SLOTS;
  }
}

// ================= fallback (round-1 kernel) if ws too small ================
#define XS_C 24
#define WS_K 168
__global__ __launch_bounds__(256, 2)
void conv_min_tanh(const float* __restrict__ xg, const float* __restrict__ wg,
                   const float* __restrict__ bg, float* __restrict__ out) {
  __shared__ __align__(16) unsigned short xs[3 * XS_W * XS_C];
  __shared__ __align__(16) unsigned short ws[CO * WS_K];
  const int t = threadIdx.x;
  const int n = blockIdx.x / OHH;
  const int oh = blockIdx.x % OHH;
#pragma unroll
  for (int i = 0; i < 36; ++i) {
    int f = i * 256 + t;
    int oc = f / 144;
    int r = f - oc * 144;
    int ci = r / 9;
    int tap = r - ci * 9;
    ws[oc * WS_K + tap * 16 + ci] = f2bf(wg[f]);
  }
  if (t < CO) ws[t * WS_K + 144] = f2bf(bg[t]);
  for (int i = t; i < CO * 15; i += 256) {
    int oc = i / 15;
    ws[oc * WS_K + 145 + (i - oc * 15)] = 0;
  }
  {
    const size_t base_n = (size_t)n * CI * HH * WW;
#pragma unroll
    for (int kh = 0; kh < 3; ++kh) {
#pragma unroll
      for (int half = 0; half < 2; ++half) {
        float v[8];
#pragma unroll
        for (int j = 0; j < 8; ++j) {
          int ci = half * 8 + j;
          v[j] = xg[base_n + ((size_t)ci * HH + (oh + kh)) * WW + t];
        }
        us8 pk;
#pragma unroll
        for (int j = 0; j < 8; ++j) pk[j] = f2bf(v[j]);
        *(us8*)(xs + (kh * XS_W + t) * XS_C + half * 8) = pk;
      }
    }
  }
  if (t < 96) {
    int kh = t >> 5;
    int rem = t & 31;
    int w = 256 + (rem >> 4);
    int ci = rem & 15;
    xs[(kh * XS_W + w) * XS_C + ci] = 0;
  }
  __syncthreads();
  const int lane = t & 63, wave = t >> 6;
  const int lr = lane & 31, qh = lane >> 5;
  bf16x8 afrag[2][10];
#pragma unroll
  for (int mt = 0; mt < 2; ++mt) {
    const unsigned short* wq = ws + (mt * 32 + lr) * WS_K + qh * 8;
#pragma unroll
    for (int tap = 0; tap < 10; ++tap)
      afrag[mt][tap] = __builtin_bit_cast(bf16x8, *(const us8*)(wq + tap * 16));
  }
  f32x16 acc[2][2];
#pragma unroll
  for (int a = 0; a < 2; ++a)
#pragma unroll
    for (int b = 0; b < 2; ++b)
#pragma unroll
      for (int e = 0; e < 16; ++e) acc[a][b][e] = 0.f;
  const unsigned short* xq = xs + (wave * 64 + lr) * XS_C + qh * 8;
#pragma unroll
  for (int tap = 0; tap < 9; ++tap) {
    const int kh = tap / 3, kw = tap - kh * 3;
#pragma unroll
    for (int nt = 0; nt < 2; ++nt) {
      bf16x8 xf = __builtin_bit_cast(
          bf16x8, *(const us8*)(xq + (kh * XS_W + nt * 32 + kw) * XS_C));
      acc[0][nt] = __builtin_amdgcn_mfma_f32_32x32x16_bf16(afrag[0][tap], xf,
                                                           acc[0][nt], 0, 0, 0);
      acc[1][nt] = __builtin_amdgcn_mfma_f32_32x32x16_bf16(afrag[1][tap], xf,
                                                           acc[1][nt], 0, 0, 0);
    }
  }
  {
    us8 one = {};
    if (qh == 0) one[0] = 0x3F80;
    bf16x8 xone = __builtin_bit_cast(bf16x8, one);
#pragma unroll
    for (int nt = 0; nt < 2; ++nt) {
      acc[0][nt] = __builtin_amdgcn_mfma_f32_32x32x16_bf16(afrag[0][9], xone,
                                                           acc[0][nt], 0, 0, 0);
      acc[1][nt] = __builtin_amdgcn_mfma_f32_32x32x16_bf16(afrag[1][9], xone,
                                                           acc[1][nt], 0, 0, 0);
    }
  }
  float vmin[2];
#pragma unroll
  for (int nt = 0; nt < 2; ++nt) {
    float v = acc[0][nt][0];
#pragma unroll
    for (int e = 1; e < 16; ++e) v = fminf(v, acc[0][nt][e]);
#pragma unroll
    for (int e = 0; e < 16; ++e) v = fminf(v, acc[1][nt][e]);
    v = fminf(v, __shfl_xor(v, 32, 64));
    vmin[nt] = fast_tanh(fast_tanh(v));
  }
  float res = (lane < 32) ? vmin[0] : vmin[1];
  int ow = wave * 64 + lane;
  if (ow < OWW) out[((size_t)n * OHH + oh) * OWW + ow] = res;
}

extern "C" void kernel_launch(void* const* d_in, const int* in_sizes, int n_in,
                              void* d_out, int out_size, void* d_ws, size_t ws_size,
                              hipStream_t stream) {
  const float* x = (const float*)d_in[0];
  const float* w = (const float*)d_in[1];
  const float* b = (const float*)d_in[2];
  float* out = (float*)d_out;
  if (ws_size >= WS_NEEDED) {
    unsigned short* wp = (unsigned short*)d_ws;
    prep_w<<<dim3((WP_SHORTS + 255) / 256), dim3(256), 0, stream>>>(w, b, wp);
    conv_fused<<<dim3(N_IMG * NSTRIP), dim3(256), 0, stream>>>(x, wp, out);
  } else {
    conv_min_tanh<<<dim3(N_IMG * OHH), dim3(256), 0, stream>>>(x, w, b, out);
  }
}

// Round 7
// 208.311 us; speedup vs baseline: 1.0467x; 1.0467x over previous
//
#include <hip/hip_runtime.h>

typedef __bf16 bf16x8 __attribute__((ext_vector_type(8)));
typedef unsigned short us8 __attribute__((ext_vector_type(8)));
typedef unsigned short us2 __attribute__((ext_vector_type(2)));
typedef float f32x16 __attribute__((ext_vector_type(16)));

#define N_IMG 32
#define CI 16
#define HH 256
#define WW 256
#define CO 64
#define OHH 254
#define OWW 254

#define XS_W 258              // 256 + 2 zero-pad columns
#define SC 24                 // shorts per (row,w) cell: 48B stride, bank-balanced
#define NSTRIP 24             // 32*24 = 768 blocks = exactly 3 resident/CU
#define WP_SHORTS (CO * 160)
#define WS_NEEDED ((size_t)WP_SHORTS * 2)

__device__ __forceinline__ unsigned short f2bf(float f) {
  union { float f; unsigned u; } v; v.f = f;
  return (unsigned short)((v.u + 0x7FFFu + ((v.u >> 16) & 1u)) >> 16);  // RNE
}

#if defined(__has_builtin)
#if __has_builtin(__builtin_amdgcn_cvt_pk_bf16_f32)
#define HAVE_CVT_PK 1
#endif
#endif

__device__ __forceinline__ us2 cvt2(float a, float b) {
#ifdef HAVE_CVT_PK
  typedef __bf16 bf16x2 __attribute__((ext_vector_type(2)));
  bf16x2 r = __builtin_amdgcn_cvt_pk_bf16_f32(a, b);  // lo=a, hi=b, RNE
  return __builtin_bit_cast(us2, r);
#else
  us2 r; r[0] = f2bf(a); r[1] = f2bf(b); return r;
#endif
}

__device__ __forceinline__ float fast_tanh(float x) {
  float cx = fminf(fmaxf(x, -15.f), 15.f);
  float e = __expf(2.f * cx);
  return (e - 1.f) / (e + 1.f);
}

// ---- prep: weights+bias -> bf16 A-side layout wp[oc][tap*16+ci] (20 KB) ----
__global__ void prep_w(const float* __restrict__ wg, const float* __restrict__ bg,
                       unsigned short* __restrict__ wp) {
  int idx = blockIdx.x * 256 + threadIdx.x;
  if (idx >= WP_SHORTS) return;
  int oc = idx / 160;
  int k = idx - oc * 160;
  int tap = k >> 4, ci = k & 15;
  float v;
  if (tap < 9)      v = wg[oc * 144 + ci * 9 + tap];
  else if (ci == 0) v = bg[oc];
  else              v = 0.f;
  wp[idx] = f2bf(v);
}

// ---- fused conv+min+tanh: rolling-window strip kernel, LATE-ISSUE prefetch --
// R3 structure (best measured, spill-free) with ONE reordering: the 16 global
// loads are issued at the BOTTOM of each iteration (row oh+4, right after the
// cvt consumes v = row oh+3), not at the top. Load-to-use distance becomes a
// FULL iteration (store+barrier+next MFMA phase, ~8-11k cyc) instead of just
// the MFMA phase (~2-3k cyc < burst-loaded HBM round trip ~5k cyc) -- the
// cvt's vmcnt wait should hit already-landed data, removing the one partially
// uncovered memory round trip per row that R0-R5 all shared (conv pinned at
// ~49us, all pipes <25%, HBM 1.2-1.7 TB/s). Register lifetime of v is the
// SAME as R3 (alive across one MFMA phase), so no new pressure -- R4/R6
// showed any added register state spills (VGPR 84 + scratch WRITE_SIZE).
// One sched_barrier(0) pins cvt+loads after the MFMA phase; plain
// __syncthreads everywhere (R2's asm-waitcnt fences wrecked regalloc).
// Ring safety unchanged from R3: iter oh reads slots oh..oh+2 (&3), cvt
// writes slot (oh+3)&3 == (oh-1)&3, last read one barrier ago.
// Numerics identical to the 213us baseline (same cvt, same MFMA order;
// fmin tree is a bit-exact reassociation; same tanh).
__global__ __launch_bounds__(256, 3)
void conv_fused(const float* __restrict__ xg, const unsigned short* __restrict__ wp,
                float* __restrict__ out) {
  __shared__ __align__(16) unsigned short xs[4 * XS_W * SC];  // 48.4 KB -> 3/CU
  const int t = threadIdx.x;
  const int n = blockIdx.x / NSTRIP;
  const int s = blockIdx.x - n * NSTRIP;
  // 254 rows over 24 strips: 14 strips of 11 rows, 10 strips of 10 rows
  const int oh0 = s * 10 + (s < 14 ? s : 14);
  const int nrows = (s < 14) ? 11 : 10;
  const int oh1 = oh0 + nrows;

  const float* srcT = xg + (size_t)n * (CI * HH * WW) + t;

  // ---- prologue: stage input rows oh0..oh0+2 into their ring slots ----
  {
    float pv[3][16];
#pragma unroll
    for (int r = 0; r < 3; ++r)
#pragma unroll
      for (int j = 0; j < 16; ++j)
        pv[r][j] = srcT[((size_t)j * HH + (oh0 + r)) * WW];
#pragma unroll
    for (int r = 0; r < 3; ++r) {
      union { us8 v8[2]; us2 v2[8]; } pk;
#pragma unroll
      for (int j = 0; j < 8; ++j) pk.v2[j] = cvt2(pv[r][2 * j], pv[r][2 * j + 1]);
      const int slot = (oh0 + r) & 3;
      *(us8*)(xs + (slot * XS_W + t) * SC) = pk.v8[0];      // ds_write_b128
      *(us8*)(xs + (slot * XS_W + t) * SC + 8) = pk.v8[1];  // ds_write_b128
    }
  }
  if (t < 128) {  // zero pad columns w=256,257 for all 4 ring slots (persist)
    const int slot = t >> 5, rem = t & 31;
    xs[(slot * XS_W + 256 + (rem >> 4)) * SC + (rem & 15)] = 0;
  }

  const int lane = t & 63, wave = t >> 6;
  const int lr = lane & 31, qh = lane >> 5;

  // preload A-frags ONCE into registers (2 mt x 10 taps x 4 VGPR = 80 VGPRs)
  const unsigned short* wpl = wp + lr * 160 + qh * 8;
  bf16x8 afrag[2][10];
#pragma unroll
  for (int mt = 0; mt < 2; ++mt)
#pragma unroll
    for (int tap = 0; tap < 10; ++tap)
      afrag[mt][tap] =
          __builtin_bit_cast(bf16x8, *(const us8*)(wpl + mt * 32 * 160 + tap * 16));

  us8 onev = {};
  if (qh == 0) onev[0] = 0x3F80;
  const bf16x8 xone = __builtin_bit_cast(bf16x8, onev);

  const int pb = wave * 64;  // this wave's 64-pixel strip

  // prime the prefetch: v <- row oh0+3 (consumed by iter oh0's cvt)
  float v[16];
#pragma unroll
  for (int j = 0; j < 16; ++j)
    v[j] = srcT[((size_t)j * HH + (oh0 + 3)) * WW];

  __syncthreads();

  for (int oh = oh0; oh < oh1; ++oh) {
    // ---- phase 1: MFMA row oh from ring slots oh..oh+2 (LDS only) ----
    float vmin[2];
#pragma unroll
    for (int nt = 0; nt < 2; ++nt) {  // sequential nt: acc = 32 VGPR not 64
      f32x16 acc0, acc1;
#pragma unroll
      for (int e = 0; e < 16; ++e) { acc0[e] = 0.f; acc1[e] = 0.f; }
#pragma unroll
      for (int tap = 0; tap < 9; ++tap) {
        const int kh = tap / 3, kw = tap - kh * 3;
        const int slot = (oh + kh) & 3;
        bf16x8 xf = __builtin_bit_cast(
            bf16x8,
            *(const us8*)(xs + (slot * XS_W + pb + nt * 32 + lr + kw) * SC + qh * 8));
        acc0 = __builtin_amdgcn_mfma_f32_32x32x16_bf16(afrag[0][tap], xf, acc0, 0, 0, 0);
        acc1 = __builtin_amdgcn_mfma_f32_32x32x16_bf16(afrag[1][tap], xf, acc1, 0, 0, 0);
      }
      // bias tap: B = e_{k=144}
      acc0 = __builtin_amdgcn_mfma_f32_32x32x16_bf16(afrag[0][9], xone, acc0, 0, 0, 0);
      acc1 = __builtin_amdgcn_mfma_f32_32x32x16_bf16(afrag[1][9], xone, acc1, 0, 0, 0);

      // tree min: depth 5 instead of a 31-deep serial chain (bit-exact)
      f32x16 m;
#pragma unroll
      for (int e = 0; e < 16; ++e) m[e] = fminf(acc0[e], acc1[e]);
#pragma unroll
      for (int e = 0; e < 8; ++e) m[e] = fminf(m[e], m[e + 8]);
#pragma unroll
      for (int e = 0; e < 4; ++e) m[e] = fminf(m[e], m[e + 4]);
      float mv = fminf(fminf(m[0], m[1]), fminf(m[2], m[3]));
      mv = fminf(mv, __shfl_xor(mv, 32, 64));
      vmin[nt] = fast_tanh(fast_tanh(mv));
    }

    // pin phase order: cvt/loads must not be hoisted above the MFMA phase,
    // or last iter's loads lose their latency cover
    __builtin_amdgcn_sched_barrier(0);

    // ---- phase 2: cvt v (row oh+3, loaded LAST iteration -> full-iter
    // cover, vmcnt wait should be free) into ring slot (oh+3)&3 ----
    if (oh + 1 < oh1) {
      union { us8 v8[2]; us2 v2[8]; } pk;
#pragma unroll
      for (int j = 0; j < 8; ++j) pk.v2[j] = cvt2(v[2 * j], v[2 * j + 1]);
      const int slot = (oh + 3) & 3;
      *(us8*)(xs + (slot * XS_W + t) * SC) = pk.v8[0];
      *(us8*)(xs + (slot * XS_W + t) * SC + 8) = pk.v8[1];
    }

    // ---- phase 3: issue loads for row oh+4 (WAR on v orders them after
    // the cvt reads; consumed by NEXT iteration's cvt) ----
    if (oh + 2 < oh1) {
#pragma unroll
      for (int j = 0; j < 16; ++j)
        v[j] = srcT[((size_t)j * HH + (oh + 4)) * WW];
    }

    // ---- phase 4: store output row oh ----
    const float res = (lane < 32) ? vmin[0] : vmin[1];
    const int ow = pb + lane;
    if (ow < OWW) out[((size_t)n * OHH + oh) * OWW + ow] = res;

    __syncthreads();
  }
}

// ================= fallback (round-1 kernel) if ws too small ================
#define XS_C 24
#define WS_K 168
__global__ __launch_bounds__(256, 2)
void conv_min_tanh(const float* __restrict__ xg, const float* __restrict__ wg,
                   const float* __restrict__ bg, float* __restrict__ out) {
  __shared__ __align__(16) unsigned short xs[3 * XS_W * XS_C];
  __shared__ __align__(16) unsigned short ws[CO * WS_K];
  const int t = threadIdx.x;
  const int n = blockIdx.x / OHH;
  const int oh = blockIdx.x % OHH;
#pragma unroll
  for (int i = 0; i < 36; ++i) {
    int f = i * 256 + t;
    int oc = f / 144;
    int r = f - oc * 144;
    int ci = r / 9;
    int tap = r - ci * 9;
    ws[oc * WS_K + tap * 16 + ci] = f2bf(wg[f]);
  }
  if (t < CO) ws[t * WS_K + 144] = f2bf(bg[t]);
  for (int i = t; i < CO * 15; i += 256) {
    int oc = i / 15;
    ws[oc * WS_K + 145 + (i - oc * 15)] = 0;
  }
  {
    const size_t base_n = (size_t)n * CI * HH * WW;
#pragma unroll
    for (int kh = 0; kh < 3; ++kh) {
#pragma unroll
      for (int half = 0; half < 2; ++half) {
        float v[8];
#pragma unroll
        for (int j = 0; j < 8; ++j) {
          int ci = half * 8 + j;
          v[j] = xg[base_n + ((size_t)ci * HH + (oh + kh)) * WW + t];
        }
        us8 pk;
#pragma unroll
        for (int j = 0; j < 8; ++j) pk[j] = f2bf(v[j]);
        *(us8*)(xs + (kh * XS_W + t) * XS_C + half * 8) = pk;
      }
    }
  }
  if (t < 96) {
    int kh = t >> 5;
    int rem = t & 31;
    int w = 256 + (rem >> 4);
    int ci = rem & 15;
    xs[(kh * XS_W + w) * XS_C + ci] = 0;
  }
  __syncthreads();
  const int lane = t & 63, wave = t >> 6;
  const int lr = lane & 31, qh = lane >> 5;
  bf16x8 afrag[2][10];
#pragma unroll
  for (int mt = 0; mt < 2; ++mt) {
    const unsigned short* wq = ws + (mt * 32 + lr) * WS_K + qh * 8;
#pragma unroll
    for (int tap = 0; tap < 10; ++tap)
      afrag[mt][tap] = __builtin_bit_cast(bf16x8, *(const us8*)(wq + tap * 16));
  }
  f32x16 acc[2][2];
#pragma unroll
  for (int a = 0; a < 2; ++a)
#pragma unroll
    for (int b = 0; b < 2; ++b)
#pragma unroll
      for (int e = 0; e < 16; ++e) acc[a][b][e] = 0.f;
  const unsigned short* xq = xs + (wave * 64 + lr) * XS_C + qh * 8;
#pragma unroll
  for (int tap = 0; tap < 9; ++tap) {
    const int kh = tap / 3, kw = tap - kh * 3;
#pragma unroll
    for (int nt = 0; nt < 2; ++nt) {
      bf16x8 xf = __builtin_bit_cast(
          bf16x8, *(const us8*)(xq + (kh * XS_W + nt * 32 + kw) * XS_C));
      acc[0][nt] = __builtin_amdgcn_mfma_f32_32x32x16_bf16(afrag[0][tap], xf,
                                                           acc[0][nt], 0, 0, 0);
      acc[1][nt] = __builtin_amdgcn_mfma_f32_32x32x16_bf16(afrag[1][tap], xf,
                                                           acc[1][nt], 0, 0, 0);
    }
  }
  {
    us8 one = {};
    if (qh == 0) one[0] = 0x3F80;
    bf16x8 xone = __builtin_bit_cast(bf16x8, one);
#pragma unroll
    for (int nt = 0; nt < 2; ++nt) {
      acc[0][nt] = __builtin_amdgcn_mfma_f32_32x32x16_bf16(afrag[0][9], xone,
                                                           acc[0][nt], 0, 0, 0);
      acc[1][nt] = __builtin_amdgcn_mfma_f32_32x32x16_bf16(afrag[1][9], xone,
                                                           acc[1][nt], 0, 0, 0);
    }
  }
  float vmin[2];
#pragma unroll
  for (int nt = 0; nt < 2; ++nt) {
    float v = acc[0][nt][0];
#pragma unroll
    for (int e = 1; e < 16; ++e) v = fminf(v, acc[0][nt][e]);
#pragma unroll
    for (int e = 0; e < 16; ++e) v = fminf(v, acc[1][nt][e]);
    v = fminf(v, __shfl_xor(v, 32, 64));
    vmin[nt] = fast_tanh(fast_tanh(v));
  }
  float res = (lane < 32) ? vmin[0] : vmin[1];
  int ow = wave * 64 + lane;
  if (ow < OWW) out[((size_t)n * OHH + oh) * OWW + ow] = res;
}

extern "C" void kernel_launch(void* const* d_in, const int* in_sizes, int n_in,
                              void* d_out, int out_size, void* d_ws, size_t ws_size,
                              hipStream_t stream) {
  const float* x = (const float*)d_in[0];
  const float* w = (const float*)d_in[1];
  const float* b = (const float*)d_in[2];
  float* out = (float*)d_out;
  if (ws_size >= WS_NEEDED) {
    unsigned short* wp = (unsigned short*)d_ws;
    prep_w<<<dim3((WP_SHORTS + 255) / 256), dim3(256), 0, stream>>>(w, b, wp);
    conv_fused<<<dim3(N_IMG * NSTRIP), dim3(256), 0, stream>>>(x, wp, out);
  } else {
    conv_min_tanh<<<dim3(N_IMG * OHH), dim3(256), 0, stream>>>(x, w, b, out);
  }
}